// Round 1
// baseline (1065.366 us; speedup 1.0000x reference)
//
#include <hip/hip_runtime.h>

#define FN   128    // nodes per graph
#define HDIM 128    // hidden dim
#define NH   4      // heads, layer 0
#define HSZ  32     // head dim, layer 0
#define EB   1024   // base edges per graph
#define ET   1152   // edges incl. self loops
#define RS   132    // padded LDS row stride (floats)

// ---------------- CSR build (topology shared by ALL graphs) ----------------
__global__ __launch_bounds__(256) void build_csr_kernel(
    const int* __restrict__ ei, int* __restrict__ rp, int* __restrict__ srcs)
{
  __shared__ int deg[FN];
  __shared__ int fill[FN];
  __shared__ int rps[FN + 1];
  const int t = threadIdx.x;
  if (t < FN) { deg[t] = 0; fill[t] = 0; }
  __syncthreads();
  for (int e = t; e < EB; e += 256) atomicAdd(&deg[ei[EB + e]], 1);
  __syncthreads();
  if (t == 0) {
    int acc = 0;
    for (int n = 0; n < FN; ++n) { rps[n] = acc; acc += deg[n] + 1; }
    rps[FN] = acc;   // == ET
  }
  __syncthreads();
  for (int e = t; e < EB; e += 256) {
    int d = ei[EB + e];
    int p = rps[d] + atomicAdd(&fill[d], 1);
    srcs[p] = ei[e];
  }
  if (t < FN) srcs[rps[t + 1] - 1] = t;  // self loop at end of each row (disjoint slot)
  if (t <= FN) rp[t] = rps[t];
}

// ---------------- per-thread column GEMM: dst = src @ W ----------------
// thread owns output column j; W column cached in 128 VGPRs (coalesced load,
// W is L2-resident across all 1024 blocks). src rows read as broadcast b128.
__device__ __forceinline__ void gemm128(float (*src)[RS], float (*dst)[RS],
                                        const float* __restrict__ W,
                                        int j, int half)
{
  float wcol[HDIM];
  #pragma unroll
  for (int k = 0; k < HDIM; ++k) wcol[k] = W[k * HDIM + j];
  const int n0 = half * 64;
  for (int n = n0; n < n0 + 64; ++n) {
    float a0 = 0.f, a1 = 0.f, a2 = 0.f, a3 = 0.f;
    #pragma unroll
    for (int k = 0; k < HDIM; k += 4) {
      const float4 hv = *(const float4*)(&src[n][k]);
      a0 = fmaf(hv.x, wcol[k + 0], a0);
      a1 = fmaf(hv.y, wcol[k + 1], a1);
      a2 = fmaf(hv.z, wcol[k + 2], a2);
      a3 = fmaf(hv.w, wcol[k + 3], a3);
    }
    dst[n][j] = (a0 + a1) + (a2 + a3);
  }
}

// ---------------- fused per-graph GNN ----------------
__global__ __launch_bounds__(256, 1) void gnn_fused_kernel(
    const float* __restrict__ x,
    const float* __restrict__ w_in, const float* __restrict__ b_in,
    const float* __restrict__ g0w, const float* __restrict__ g0as,
    const float* __restrict__ g0ad, const float* __restrict__ g0b,
    const float* __restrict__ bn0g, const float* __restrict__ bn0b,
    const float* __restrict__ bn0m, const float* __restrict__ bn0v,
    const float* __restrict__ g1w, const float* __restrict__ g1as,
    const float* __restrict__ g1ad, const float* __restrict__ g1b,
    const float* __restrict__ bn1g, const float* __restrict__ bn1b,
    const float* __restrict__ bn1m, const float* __restrict__ bn1v,
    const float* __restrict__ w1, const float* __restrict__ b1,
    const float* __restrict__ w2, const float* __restrict__ b2,
    const int* __restrict__ rp, const int* __restrict__ srcs,
    float* __restrict__ out)
{
  __shared__ float sh[FN][RS];      // features (h), also aggregation output
  __shared__ float sg[FN][RS];      // transformed features (xh)
  __shared__ float s_es[FN][NH];
  __shared__ float s_ed[FN][NH];
  __shared__ float s_m[FN][NH];
  __shared__ float s_sum[FN][NH];
  __shared__ float s_red[256];
  __shared__ float s_x[FN];
  __shared__ int   s_rp[FN + 1];
  __shared__ int   s_src[ET];

  const int t    = threadIdx.x;
  const int b    = blockIdx.x;
  const int j    = t & 127;
  const int half = t >> 7;
  const int n0   = half * 64;

  for (int i = t; i < FN + 1; i += 256) s_rp[i] = rp[i];
  for (int i = t; i < ET; i += 256)     s_src[i] = srcs[i];
  if (t < FN) s_x[t] = x[(size_t)b * FN + t];
  __syncthreads();

  // ---- input projection + ReLU: h = relu(x * w_in + b_in)
  {
    const float wv = w_in[j], bv = b_in[j];
    for (int n = half; n < FN; n += 2) {
      float v = fmaf(s_x[n], wv, bv);
      sh[n][j] = v > 0.f ? v : 0.f;
    }
  }
  __syncthreads();

  // ======================= GAT layer 0 (4 heads, concat) =======================
  gemm128(sh, sg, g0w, j, half);
  __syncthreads();

  // attention logits per (node, head)
  for (int it = t; it < FN * NH; it += 256) {
    const int n = it & 127, hh = it >> 7;
    float accs = 0.f, accd = 0.f;
    #pragma unroll
    for (int d = 0; d < HSZ; d += 4) {
      const float4 v  = *(const float4*)(&sg[n][hh * HSZ + d]);
      const float4 as = *(const float4*)(&g0as[hh * HSZ + d]);
      const float4 ad = *(const float4*)(&g0ad[hh * HSZ + d]);
      accs += v.x*as.x + v.y*as.y + v.z*as.z + v.w*as.w;
      accd += v.x*ad.x + v.y*ad.y + v.z*ad.z + v.w*ad.w;
    }
    s_es[n][hh] = accs;
    s_ed[n][hh] = accd;
  }
  __syncthreads();

  // softmax stats (max, sum) per (dst, head)
  for (int it = t; it < FN * NH; it += 256) {
    const int n = it & 127, hh = it >> 7;
    const float edv = s_ed[n][hh];
    const int e0 = s_rp[n], e1 = s_rp[n + 1];
    float mv = -1e30f;
    for (int e = e0; e < e1; ++e) {
      float v = s_es[s_src[e]][hh] + edv;
      v = v > 0.f ? v : 0.2f * v;
      mv = fmaxf(mv, v);
    }
    float sv = 0.f;
    for (int e = e0; e < e1; ++e) {
      float v = s_es[s_src[e]][hh] + edv;
      v = v > 0.f ? v : 0.2f * v;
      sv += __expf(v - mv);
    }
    s_m[n][hh] = mv;
    s_sum[n][hh] = sv;
  }
  __syncthreads();

  // aggregation + bias + BN + ReLU  -> sh
  {
    const int hh = j >> 5;
    const float bb = g0b[j];
    const float bm = bn0m[j];
    const float rstd = rsqrtf(bn0v[j] + 1e-5f);
    const float gg = bn0g[j] * rstd, bt = bn0b[j];
    for (int n = n0; n < n0 + 64; ++n) {
      const float edv = s_ed[n][hh];
      const float mv  = s_m[n][hh];
      const float rsv = 1.f / s_sum[n][hh];
      const int e0 = s_rp[n], e1 = s_rp[n + 1];
      float acc = 0.f;
      for (int e = e0; e < e1; ++e) {
        const int s = s_src[e];
        float v = s_es[s][hh] + edv;
        v = v > 0.f ? v : 0.2f * v;
        acc = fmaf(__expf(v - mv), sg[s][j], acc);
      }
      float val = acc * rsv + bb;
      val = (val - bm) * gg + bt;
      sh[n][j] = val > 0.f ? val : 0.f;
    }
  }
  __syncthreads();

  // ======================= GAT layer 1 (1 head, no concat) =======================
  gemm128(sh, sg, g1w, j, half);
  __syncthreads();

  if (t < FN) {
    const int n = t;
    float accs = 0.f, accd = 0.f;
    #pragma unroll
    for (int k = 0; k < HDIM; k += 4) {
      const float4 v  = *(const float4*)(&sg[n][k]);
      const float4 as = *(const float4*)(&g1as[k]);
      const float4 ad = *(const float4*)(&g1ad[k]);
      accs += v.x*as.x + v.y*as.y + v.z*as.z + v.w*as.w;
      accd += v.x*ad.x + v.y*ad.y + v.z*ad.z + v.w*ad.w;
    }
    s_es[n][0] = accs;
    s_ed[n][0] = accd;
  }
  __syncthreads();

  if (t < FN) {
    const int n = t;
    const float edv = s_ed[n][0];
    const int e0 = s_rp[n], e1 = s_rp[n + 1];
    float mv = -1e30f;
    for (int e = e0; e < e1; ++e) {
      float v = s_es[s_src[e]][0] + edv;
      v = v > 0.f ? v : 0.2f * v;
      mv = fmaxf(mv, v);
    }
    float sv = 0.f;
    for (int e = e0; e < e1; ++e) {
      float v = s_es[s_src[e]][0] + edv;
      v = v > 0.f ? v : 0.2f * v;
      sv += __expf(v - mv);
    }
    s_m[n][0] = mv;
    s_sum[n][0] = sv;
  }
  __syncthreads();

  {
    const float bb = g1b[j];
    const float bm = bn1m[j];
    const float rstd = rsqrtf(bn1v[j] + 1e-5f);
    const float gg = bn1g[j] * rstd, bt = bn1b[j];
    for (int n = n0; n < n0 + 64; ++n) {
      const float edv = s_ed[n][0];
      const float mv  = s_m[n][0];
      const float rsv = 1.f / s_sum[n][0];
      const int e0 = s_rp[n], e1 = s_rp[n + 1];
      float acc = 0.f;
      for (int e = e0; e < e1; ++e) {
        const int s = s_src[e];
        float v = s_es[s][0] + edv;
        v = v > 0.f ? v : 0.2f * v;
        acc = fmaf(__expf(v - mv), sg[s][j], acc);
      }
      float val = acc * rsv + bb;
      val = (val - bm) * gg + bt;
      sh[n][j] = val > 0.f ? val : 0.f;
    }
  }
  __syncthreads();

  // ---- mean pool over nodes, then MLP head
  {
    float p = 0.f;
    for (int n = n0; n < n0 + 64; ++n) p += sh[n][j];
    s_red[t] = p;
  }
  __syncthreads();
  if (t < FN) s_x[t] = (s_red[t] + s_red[t + 128]) * (1.f / 128.f);
  __syncthreads();
  if (t < 64) {
    float a = b1[t];
    #pragma unroll 4
    for (int k = 0; k < HDIM; ++k) a = fmaf(s_x[k], w1[k * 64 + t], a);
    a = a > 0.f ? a : 0.f;
    float v = a * w2[t];
    #pragma unroll
    for (int off = 32; off > 0; off >>= 1) v += __shfl_down(v, off, 64);
    if (t == 0) out[b] = v + b2[0];
  }
}

extern "C" void kernel_launch(void* const* d_in, const int* in_sizes, int n_in,
                              void* d_out, int out_size, void* d_ws, size_t ws_size,
                              hipStream_t stream)
{
  const float* x    = (const float*)d_in[0];
  const int*   ei   = (const int*)d_in[1];
  const float* w_in = (const float*)d_in[2];
  const float* b_in = (const float*)d_in[3];
  const float* g0w  = (const float*)d_in[4];
  const float* g0as = (const float*)d_in[5];
  const float* g0ad = (const float*)d_in[6];
  const float* g0b  = (const float*)d_in[7];
  const float* bn0g = (const float*)d_in[8];
  const float* bn0b = (const float*)d_in[9];
  const float* bn0m = (const float*)d_in[10];
  const float* bn0v = (const float*)d_in[11];
  const float* g1w  = (const float*)d_in[12];
  const float* g1as = (const float*)d_in[13];
  const float* g1ad = (const float*)d_in[14];
  const float* g1b  = (const float*)d_in[15];
  const float* bn1g = (const float*)d_in[16];
  const float* bn1b = (const float*)d_in[17];
  const float* bn1m = (const float*)d_in[18];
  const float* bn1v = (const float*)d_in[19];
  const float* w1   = (const float*)d_in[20];
  const float* b1   = (const float*)d_in[21];
  const float* w2   = (const float*)d_in[22];
  const float* b2   = (const float*)d_in[23];

  int* rp   = (int*)d_ws;       // 129 ints
  int* srcs = rp + 256;         // 1152 ints (aligned headroom)

  build_csr_kernel<<<1, 256, 0, stream>>>(ei, rp, srcs);
  gnn_fused_kernel<<<1024, 256, 0, stream>>>(x, w_in, b_in,
      g0w, g0as, g0ad, g0b, bn0g, bn0b, bn0m, bn0v,
      g1w, g1as, g1ad, g1b, bn1g, bn1b, bn1m, bn1v,
      w1, b1, w2, b2, rp, srcs, (float*)d_out);
}

// Round 2
// 332.346 us; speedup vs baseline: 3.2056x; 3.2056x over previous
//
#include <hip/hip_runtime.h>

#define FN   128    // nodes per graph
#define HDIM 128    // hidden dim
#define NH   4      // heads, layer 0
#define HSZ  32     // head dim, layer 0
#define EB   1024   // base edges per graph
#define ET   1152   // edges incl. self loops

// ---------------- CSR build (topology shared by ALL graphs) ----------------
__global__ __launch_bounds__(256) void build_csr_kernel(
    const int* __restrict__ ei, int* __restrict__ rp, int* __restrict__ srcs)
{
  __shared__ int deg[FN];
  __shared__ int fill[FN];
  __shared__ int rps[FN + 1];
  const int t = threadIdx.x;
  if (t < FN) { deg[t] = 0; fill[t] = 0; }
  __syncthreads();
  for (int e = t; e < EB; e += 256) atomicAdd(&deg[ei[EB + e]], 1);
  __syncthreads();
  if (t == 0) {
    int acc = 0;
    for (int n = 0; n < FN; ++n) { rps[n] = acc; acc += deg[n] + 1; }
    rps[FN] = acc;   // == ET
  }
  __syncthreads();
  for (int e = t; e < EB; e += 256) {
    int d = ei[EB + e];
    int p = rps[d] + atomicAdd(&fill[d], 1);
    srcs[p] = ei[e];
  }
  if (t < FN) srcs[rps[t + 1] - 1] = t;  // self loop at end of each row
  if (t <= FN) rp[t] = rps[t];
}

#define FMA4(A, WV, ACC)                                        \
  ACC.x = fmaf(A, WV.x, ACC.x); ACC.y = fmaf(A, WV.y, ACC.y);   \
  ACC.z = fmaf(A, WV.z, ACC.z); ACC.w = fmaf(A, WV.w, ACC.w);

// register-tiled 128x128x128 GEMM: dst = src @ W (W row-major [k][c], from L2)
// thread tile: 8 rows x 4 cols. A-reads: 2 distinct addrs/wave-instr (free).
__device__ __forceinline__ void gemm_tile(const float (*src)[HDIM],
                                          float (*dst)[HDIM],
                                          const float* __restrict__ W, int t)
{
  const int c0 = (t & 31) * 4;
  const int r0 = (t >> 5) * 8;
  float4 acc[8];
  #pragma unroll
  for (int i = 0; i < 8; ++i) acc[i] = make_float4(0.f, 0.f, 0.f, 0.f);
  #pragma unroll 2
  for (int k = 0; k < HDIM; k += 4) {
    const float4 w0 = *(const float4*)&W[(k + 0) * HDIM + c0];
    const float4 w1 = *(const float4*)&W[(k + 1) * HDIM + c0];
    const float4 w2 = *(const float4*)&W[(k + 2) * HDIM + c0];
    const float4 w3 = *(const float4*)&W[(k + 3) * HDIM + c0];
    #pragma unroll
    for (int i = 0; i < 8; ++i) {
      const float4 a = *(const float4*)&src[r0 + i][k];
      FMA4(a.x, w0, acc[i]);
      FMA4(a.y, w1, acc[i]);
      FMA4(a.z, w2, acc[i]);
      FMA4(a.w, w3, acc[i]);
    }
  }
  #pragma unroll
  for (int i = 0; i < 8; ++i) *(float4*)&dst[r0 + i][c0] = acc[i];
}

// ---------------- fused per-graph GNN (512 threads) ----------------
__global__ __launch_bounds__(512, 2) void gnn_fused_kernel(
    const float* __restrict__ x,
    const float* __restrict__ w_in, const float* __restrict__ b_in,
    const float* __restrict__ g0w, const float* __restrict__ g0as,
    const float* __restrict__ g0ad, const float* __restrict__ g0b,
    const float* __restrict__ bn0g, const float* __restrict__ bn0b,
    const float* __restrict__ bn0m, const float* __restrict__ bn0v,
    const float* __restrict__ g1w, const float* __restrict__ g1as,
    const float* __restrict__ g1ad, const float* __restrict__ g1b,
    const float* __restrict__ bn1g, const float* __restrict__ bn1b,
    const float* __restrict__ bn1m, const float* __restrict__ bn1v,
    const float* __restrict__ w1, const float* __restrict__ b1,
    const float* __restrict__ w2, const float* __restrict__ b2,
    const int* __restrict__ rp, const int* __restrict__ srcs,
    float* __restrict__ out)
{
  __shared__ float sh[FN][HDIM];        // 64 KB features
  __shared__ float sg[FN][HDIM];        // 64 KB transformed features
  __shared__ float s_alpha[ET * NH];    // 18 KB attention weights (L1 reuses [0..ET))
  __shared__ int   s_src[ET];
  __shared__ int   s_rp[FN + 1];
  __shared__ float s_es[FN * NH];
  __shared__ float s_ed[FN * NH];
  __shared__ float s_x[FN];

  const int t = threadIdx.x;
  const int b = blockIdx.x;

  for (int i = t; i < FN + 1; i += 512) s_rp[i] = rp[i];
  for (int i = t; i < ET; i += 512)     s_src[i] = srcs[i];
  if (t < FN) s_x[t] = x[(size_t)b * FN + t];
  __syncthreads();

  // ---- input projection + ReLU
  {
    const int j = t & 127, q = t >> 7;
    const float wv = w_in[j], bv = b_in[j];
    for (int n = q * 32; n < q * 32 + 32; ++n)
      sh[n][j] = fmaxf(fmaf(s_x[n], wv, bv), 0.f);
  }
  __syncthreads();

  // ======================= GAT layer 0 =======================
  gemm_tile(sh, sg, g0w, t);
  __syncthreads();

  // logits es/ed per (node, head); bank-rotated reads (conflict-free)
  {
    const int n = t >> 2, hh = t & 3;
    const int base = hh * HSZ;
    const int rot = t & 31;
    float accs = 0.f, accd = 0.f;
    #pragma unroll 4
    for (int s = 0; s < HSZ; ++s) {
      const int d = (rot + s) & 31;
      const float v = sg[n][base + d];
      accs = fmaf(v, g0as[base + d], accs);
      accd = fmaf(v, g0ad[base + d], accd);
    }
    s_es[n * NH + hh] = accs;
    s_ed[n * NH + hh] = accd;
  }
  __syncthreads();

  // softmax stats + normalized alpha per (edge, head)
  {
    const int n = t >> 2, hh = t & 3;
    const float edv = s_ed[n * NH + hh];
    const int e0 = s_rp[n], e1 = s_rp[n + 1];
    float mv = -1e30f;
    for (int e = e0; e < e1; ++e) {
      float v = s_es[s_src[e] * NH + hh] + edv;
      v = (v > 0.f) ? v : 0.2f * v;
      mv = fmaxf(mv, v);
    }
    float sum = 0.f;
    for (int e = e0; e < e1; ++e) {
      float v = s_es[s_src[e] * NH + hh] + edv;
      v = (v > 0.f) ? v : 0.2f * v;
      const float ex = __expf(v - mv);
      s_alpha[e * NH + hh] = ex;
      sum += ex;
    }
    const float r = 1.f / sum;
    for (int e = e0; e < e1; ++e) s_alpha[e * NH + hh] *= r;
  }
  __syncthreads();

  // aggregation + bias + BN + ReLU -> sh  (thread: 8 nodes x 4 cols)
  {
    const int cg = t & 31, c0 = cg * 4, hh = cg >> 3;
    const int rg = t >> 5;
    const float4 bb = *(const float4*)&g0b[c0];
    const float4 bm = *(const float4*)&bn0m[c0];
    const float4 bv = *(const float4*)&bn0v[c0];
    const float4 bgm = *(const float4*)&bn0g[c0];
    const float4 bbt = *(const float4*)&bn0b[c0];
    const float gx = bgm.x * rsqrtf(bv.x + 1e-5f);
    const float gy = bgm.y * rsqrtf(bv.y + 1e-5f);
    const float gz = bgm.z * rsqrtf(bv.z + 1e-5f);
    const float gw = bgm.w * rsqrtf(bv.w + 1e-5f);
    for (int n = rg * 8; n < rg * 8 + 8; ++n) {
      const int e0 = s_rp[n], e1 = s_rp[n + 1];
      float4 acc = make_float4(0.f, 0.f, 0.f, 0.f);
      for (int e = e0; e < e1; ++e) {
        const int s = s_src[e];
        const float al = s_alpha[e * NH + hh];
        const float4 v = *(const float4*)&sg[s][c0];
        FMA4(al, v, acc);
      }
      float4 o;
      o.x = fmaxf((acc.x + bb.x - bm.x) * gx + bbt.x, 0.f);
      o.y = fmaxf((acc.y + bb.y - bm.y) * gy + bbt.y, 0.f);
      o.z = fmaxf((acc.z + bb.z - bm.z) * gz + bbt.z, 0.f);
      o.w = fmaxf((acc.w + bb.w - bm.w) * gw + bbt.w, 0.f);
      *(float4*)&sh[n][c0] = o;
    }
  }
  __syncthreads();

  // ======================= GAT layer 1 =======================
  gemm_tile(sh, sg, g1w, t);
  __syncthreads();

  if (t < FN) {
    const int n = t;
    float accs = 0.f, accd = 0.f;
    #pragma unroll 4
    for (int s = 0; s < HDIM; ++s) {
      const int d = (t + s) & 127;
      const float v = sg[n][d];
      accs = fmaf(v, g1as[d], accs);
      accd = fmaf(v, g1ad[d], accd);
    }
    s_es[n] = accs;
    s_ed[n] = accd;
  }
  __syncthreads();

  if (t < FN) {
    const int n = t;
    const float edv = s_ed[n];
    const int e0 = s_rp[n], e1 = s_rp[n + 1];
    float mv = -1e30f;
    for (int e = e0; e < e1; ++e) {
      float v = s_es[s_src[e]] + edv;
      v = (v > 0.f) ? v : 0.2f * v;
      mv = fmaxf(mv, v);
    }
    float sum = 0.f;
    for (int e = e0; e < e1; ++e) {
      float v = s_es[s_src[e]] + edv;
      v = (v > 0.f) ? v : 0.2f * v;
      const float ex = __expf(v - mv);
      s_alpha[e] = ex;
      sum += ex;
    }
    const float r = 1.f / sum;
    for (int e = e0; e < e1; ++e) s_alpha[e] *= r;
  }
  __syncthreads();

  {
    const int cg = t & 31, c0 = cg * 4;
    const int rg = t >> 5;
    const float4 bb = *(const float4*)&g1b[c0];
    const float4 bm = *(const float4*)&bn1m[c0];
    const float4 bv = *(const float4*)&bn1v[c0];
    const float4 bgm = *(const float4*)&bn1g[c0];
    const float4 bbt = *(const float4*)&bn1b[c0];
    const float gx = bgm.x * rsqrtf(bv.x + 1e-5f);
    const float gy = bgm.y * rsqrtf(bv.y + 1e-5f);
    const float gz = bgm.z * rsqrtf(bv.z + 1e-5f);
    const float gw = bgm.w * rsqrtf(bv.w + 1e-5f);
    for (int n = rg * 8; n < rg * 8 + 8; ++n) {
      const int e0 = s_rp[n], e1 = s_rp[n + 1];
      float4 acc = make_float4(0.f, 0.f, 0.f, 0.f);
      for (int e = e0; e < e1; ++e) {
        const int s = s_src[e];
        const float al = s_alpha[e];
        const float4 v = *(const float4*)&sg[s][c0];
        FMA4(al, v, acc);
      }
      float4 o;
      o.x = fmaxf((acc.x + bb.x - bm.x) * gx + bbt.x, 0.f);
      o.y = fmaxf((acc.y + bb.y - bm.y) * gy + bbt.y, 0.f);
      o.z = fmaxf((acc.z + bb.z - bm.z) * gz + bbt.z, 0.f);
      o.w = fmaxf((acc.w + bb.w - bm.w) * gw + bbt.w, 0.f);
      *(float4*)&sh[n][c0] = o;
    }
  }
  __syncthreads();

  // ---- mean pool + MLP head
  float* s_red = s_alpha;   // alpha is dead now
  {
    const int j = t & 127, q = t >> 7;
    float p = 0.f;
    for (int n = q * 32; n < q * 32 + 32; ++n) p += sh[n][j];
    s_red[t] = p;
  }
  __syncthreads();
  if (t < FN)
    s_x[t] = (s_red[t] + s_red[t + 128] + s_red[t + 256] + s_red[t + 384]) * (1.f / 128.f);
  __syncthreads();
  if (t < 64) {
    float a = b1[t];
    #pragma unroll 4
    for (int k = 0; k < HDIM; ++k) a = fmaf(s_x[k], w1[k * 64 + t], a);
    a = fmaxf(a, 0.f);
    float v = a * w2[t];
    #pragma unroll
    for (int off = 32; off > 0; off >>= 1) v += __shfl_down(v, off, 64);
    if (t == 0) out[b] = v + b2[0];
  }
}

extern "C" void kernel_launch(void* const* d_in, const int* in_sizes, int n_in,
                              void* d_out, int out_size, void* d_ws, size_t ws_size,
                              hipStream_t stream)
{
  const float* x    = (const float*)d_in[0];
  const int*   ei   = (const int*)d_in[1];
  const float* w_in = (const float*)d_in[2];
  const float* b_in = (const float*)d_in[3];
  const float* g0w  = (const float*)d_in[4];
  const float* g0as = (const float*)d_in[5];
  const float* g0ad = (const float*)d_in[6];
  const float* g0b  = (const float*)d_in[7];
  const float* bn0g = (const float*)d_in[8];
  const float* bn0b = (const float*)d_in[9];
  const float* bn0m = (const float*)d_in[10];
  const float* bn0v = (const float*)d_in[11];
  const float* g1w  = (const float*)d_in[12];
  const float* g1as = (const float*)d_in[13];
  const float* g1ad = (const float*)d_in[14];
  const float* g1b  = (const float*)d_in[15];
  const float* bn1g = (const float*)d_in[16];
  const float* bn1b = (const float*)d_in[17];
  const float* bn1m = (const float*)d_in[18];
  const float* bn1v = (const float*)d_in[19];
  const float* w1   = (const float*)d_in[20];
  const float* b1   = (const float*)d_in[21];
  const float* w2   = (const float*)d_in[22];
  const float* b2   = (const float*)d_in[23];

  int* rp   = (int*)d_ws;       // 129 ints
  int* srcs = rp + 256;         // 1152 ints

  build_csr_kernel<<<1, 256, 0, stream>>>(ei, rp, srcs);
  gnn_fused_kernel<<<1024, 512, 0, stream>>>(x, w_in, b_in,
      g0w, g0as, g0ad, g0b, bn0g, bn0b, bn0m, bn0v,
      g1w, g1as, g1ad, g1b, bn1g, bn1b, bn1m, bn1v,
      w1, b1, w2, b2, rp, srcs, (float*)d_out);
}

// Round 3
// 230.831 us; speedup vs baseline: 4.6154x; 1.4398x over previous
//
#include <hip/hip_runtime.h>

#define FN   128    // nodes per graph
#define HDIM 128    // hidden dim
#define NH   4      // heads, layer 0
#define HSZ  32     // head dim, layer 0
#define EB   1024   // base edges per graph
#define ET   1152   // edges incl. self loops
#define RSW  132    // padded LDS row stride (words)

typedef __attribute__((ext_vector_type(8))) short bf16x8;
typedef __attribute__((ext_vector_type(4))) float f32x4;
typedef unsigned int u32;
typedef unsigned short u16;

// ---------------- CSR build (topology shared by ALL graphs) ----------------
__global__ __launch_bounds__(256) void build_csr_kernel(
    const int* __restrict__ ei, int* __restrict__ rp, int* __restrict__ srcs)
{
  __shared__ int deg[FN];
  __shared__ int fill[FN];
  __shared__ int rps[FN + 1];
  const int t = threadIdx.x;
  if (t < FN) { deg[t] = 0; fill[t] = 0; }
  __syncthreads();
  for (int e = t; e < EB; e += 256) atomicAdd(&deg[ei[EB + e]], 1);
  __syncthreads();
  if (t == 0) {
    int acc = 0;
    for (int n = 0; n < FN; ++n) { rps[n] = acc; acc += deg[n] + 1; }
    rps[FN] = acc;
  }
  __syncthreads();
  for (int e = t; e < EB; e += 256) {
    int d = ei[EB + e];
    int p = rps[d] + atomicAdd(&fill[d], 1);
    srcs[p] = ei[e];
  }
  if (t < FN) srcs[rps[t + 1] - 1] = t;
  if (t <= FN) rp[t] = rps[t];
}

// ---------------- W -> split bf16 hi/lo, B-fragment layout ----------------
// wf layout: [layer 2][hilo 2][ctile 8][kc 4][lane 64][j 8] bf16
// B-frag (16x16x32): lane l holds B[k = kc*32 + (l>>4)*8 + j][n = c*16 + (l&15)]
__global__ __launch_bounds__(256) void prep_w_kernel(
    const float* __restrict__ g0w, const float* __restrict__ g1w,
    u16* __restrict__ wf)
{
  const int idx = blockIdx.x * 256 + threadIdx.x;   // 32768 total
  const int layer = idx >> 14;
  const int r = idx & 16383;
  const int c  = r >> 11;
  const int kc = (r >> 9) & 3;
  const int l  = (r >> 3) & 63;
  const int j  = r & 7;
  const int k = kc * 32 + (l >> 4) * 8 + j;
  const int n = c * 16 + (l & 15);
  const float* W = layer ? g1w : g0w;
  const float v = W[k * HDIM + n];
  const u32 u = __float_as_uint(v);
  const u32 hib = u & 0xFFFF0000u;
  const float lo = v - __uint_as_float(hib);
  wf[layer * 32768 + r]         = (u16)(u >> 16);
  wf[layer * 32768 + 16384 + r] = (u16)(__float_as_uint(lo) >> 16);
}

// ---------------- helpers ----------------
__device__ __forceinline__ u32 pack_hl(float v) {
  const u32 u = __float_as_uint(v);
  const u32 hib = u & 0xFFFF0000u;
  const float lo = v - __uint_as_float(hib);
  return hib | (__float_as_uint(lo) >> 16);
}
__device__ __forceinline__ float unpack_val(u32 p) {
  return __uint_as_float(p & 0xFFFF0000u) + __uint_as_float(p << 16);
}

union U8 { bf16x8 v; u32 u[4]; };

__device__ __forceinline__ void unpack_frag(const u32* __restrict__ q,
                                            bf16x8& hi, bf16x8& lo)
{
  const uint4 p0 = *(const uint4*)(q);
  const uint4 p1 = *(const uint4*)(q + 4);
  U8 H, L;
  H.u[0] = (p0.x >> 16) | (p0.y & 0xFFFF0000u);
  L.u[0] = (p0.x & 0xFFFFu) | (p0.y << 16);
  H.u[1] = (p0.z >> 16) | (p0.w & 0xFFFF0000u);
  L.u[1] = (p0.z & 0xFFFFu) | (p0.w << 16);
  H.u[2] = (p1.x >> 16) | (p1.y & 0xFFFF0000u);
  L.u[2] = (p1.x & 0xFFFFu) | (p1.y << 16);
  H.u[3] = (p1.z >> 16) | (p1.w & 0xFFFF0000u);
  L.u[3] = (p1.z & 0xFFFFu) | (p1.w << 16);
  hi = H.v; lo = L.v;
}

// MFMA GEMM: sg[128][132] (f32) = unpack(shl) @ W   via bf16x3
// wave w: col-tile c=w&7 (16 cols), row-half rh=w>>3 (4 stripes of 16 rows)
__device__ __forceinline__ void mfma_gemm(const u32* __restrict__ shl,
                                          float* __restrict__ sg,
                                          const u16* __restrict__ wf, int t)
{
  const int w = t >> 6, lane = t & 63;
  const int c = w & 7, rh = w >> 3;
  const int m = lane & 15, quad = lane >> 4;

  bf16x8 bhi[4], blo[4];
  #pragma unroll
  for (int kc = 0; kc < 4; ++kc) {
    const u16* bp = wf + ((c * 4 + kc) * 64 + lane) * 8;
    bhi[kc] = *(const bf16x8*)bp;
    blo[kc] = *(const bf16x8*)(bp + 16384);
  }
  f32x4 acc[4];
  #pragma unroll
  for (int s = 0; s < 4; ++s) acc[s] = (f32x4){0.f, 0.f, 0.f, 0.f};

  #pragma unroll
  for (int s = 0; s < 4; ++s) {
    const int row = (rh * 4 + s) * 16 + m;
    const u32* ap = shl + row * RSW + quad * 8;
    #pragma unroll
    for (int kc = 0; kc < 4; ++kc) {
      bf16x8 ahi, alo;
      unpack_frag(ap + kc * 32, ahi, alo);
      acc[s] = __builtin_amdgcn_mfma_f32_16x16x32_bf16(ahi, bhi[kc], acc[s], 0, 0, 0);
      acc[s] = __builtin_amdgcn_mfma_f32_16x16x32_bf16(alo, bhi[kc], acc[s], 0, 0, 0);
      acc[s] = __builtin_amdgcn_mfma_f32_16x16x32_bf16(ahi, blo[kc], acc[s], 0, 0, 0);
    }
  }
  // C/D layout: col = lane&15, row = quad*4 + reg
  #pragma unroll
  for (int s = 0; s < 4; ++s) {
    const int row0 = (rh * 4 + s) * 16 + quad * 4;
    #pragma unroll
    for (int r = 0; r < 4; ++r)
      sg[(row0 + r) * RSW + c * 16 + m] = acc[s][r];
  }
}

#define FMA4(A, WV, ACC)                                        \
  ACC.x = fmaf(A, WV.x, ACC.x); ACC.y = fmaf(A, WV.y, ACC.y);   \
  ACC.z = fmaf(A, WV.z, ACC.z); ACC.w = fmaf(A, WV.w, ACC.w);

// ---------------- fused per-graph GNN (1024 threads, 16 waves) ----------------
__global__ __launch_bounds__(1024) void gnn_fused_kernel(
    const float* __restrict__ x,
    const float* __restrict__ w_in, const float* __restrict__ b_in,
    const float* __restrict__ g0as, const float* __restrict__ g0ad,
    const float* __restrict__ g0b,
    const float* __restrict__ bn0g, const float* __restrict__ bn0b,
    const float* __restrict__ bn0m, const float* __restrict__ bn0v,
    const float* __restrict__ g1as, const float* __restrict__ g1ad,
    const float* __restrict__ g1b,
    const float* __restrict__ bn1g, const float* __restrict__ bn1b,
    const float* __restrict__ bn1m, const float* __restrict__ bn1v,
    const float* __restrict__ w1, const float* __restrict__ b1,
    const float* __restrict__ w2, const float* __restrict__ b2,
    const int* __restrict__ rp, const int* __restrict__ srcs,
    const u16* __restrict__ wf,
    float* __restrict__ out)
{
  __shared__ u32   shl[FN * RSW];       // 67584 B  packed hi|lo bf16 features
  __shared__ float sg[FN * RSW];        // 67584 B  GEMM output (f32)
  __shared__ float s_alpha[ET * NH];    // 18432 B  (reused as pooling scratch)
  __shared__ int   s_src[ET];
  __shared__ int   s_rp[FN + 1];
  __shared__ float s_es[512];
  __shared__ float s_ed[512];

  const int t = threadIdx.x;
  const int b = blockIdx.x;

  for (int i = t; i < FN + 1; i += 1024) s_rp[i] = rp[i];
  for (int i = t; i < ET; i += 1024)     s_src[i] = srcs[i];

  // ---- input projection + ReLU -> shl
  {
    const int j = t & 127, q = t >> 7;
    const float wv = w_in[j], bv = b_in[j];
    for (int n = q * 16; n < q * 16 + 16; ++n) {
      const float v = fmaxf(fmaf(x[(size_t)b * FN + n], wv, bv), 0.f);
      shl[n * RSW + j] = pack_hl(v);
    }
  }
  __syncthreads();

  // ======================= GAT layer 0 =======================
  mfma_gemm(shl, sg, wf, t);
  __syncthreads();

  // logits per (node, head), rotated f4 reads
  if (t < 512) {
    const int n = t >> 2, hh = t & 3;
    const float* row = sg + n * RSW + hh * HSZ;
    float accs = 0.f, accd = 0.f;
    #pragma unroll
    for (int s = 0; s < 8; ++s) {
      const int d = ((n + s) & 7) * 4;
      const float4 v  = *(const float4*)(row + d);
      const float4 as = *(const float4*)(g0as + hh * HSZ + d);
      const float4 ad = *(const float4*)(g0ad + hh * HSZ + d);
      accs += v.x*as.x + v.y*as.y + v.z*as.z + v.w*as.w;
      accd += v.x*ad.x + v.y*ad.y + v.z*ad.z + v.w*ad.w;
    }
    s_es[n * NH + hh] = accs;
    s_ed[n * NH + hh] = accd;
  }
  __syncthreads();

  // softmax -> normalized alpha
  if (t < 512) {
    const int n = t >> 2, hh = t & 3;
    const float edv = s_ed[n * NH + hh];
    const int e0 = s_rp[n], e1 = s_rp[n + 1];
    float mv = -1e30f;
    for (int e = e0; e < e1; ++e) {
      float v = s_es[s_src[e] * NH + hh] + edv;
      v = (v > 0.f) ? v : 0.2f * v;
      mv = fmaxf(mv, v);
    }
    float sum = 0.f;
    for (int e = e0; e < e1; ++e) {
      float v = s_es[s_src[e] * NH + hh] + edv;
      v = (v > 0.f) ? v : 0.2f * v;
      const float ex = __expf(v - mv);
      s_alpha[e * NH + hh] = ex;
      sum += ex;
    }
    const float r = 1.f / sum;
    for (int e = e0; e < e1; ++e) s_alpha[e * NH + hh] *= r;
  }
  __syncthreads();

  // aggregation + bias + BN + ReLU -> shl   (thread: 4 nodes x 4 cols)
  {
    const int cg = t & 31, c0 = cg * 4, hh = cg >> 3;
    const int rg = t >> 5;
    const float4 bb = *(const float4*)&g0b[c0];
    const float4 bm = *(const float4*)&bn0m[c0];
    const float4 bv = *(const float4*)&bn0v[c0];
    const float4 bgm = *(const float4*)&bn0g[c0];
    const float4 bbt = *(const float4*)&bn0b[c0];
    const float gx = bgm.x * rsqrtf(bv.x + 1e-5f);
    const float gy = bgm.y * rsqrtf(bv.y + 1e-5f);
    const float gz = bgm.z * rsqrtf(bv.z + 1e-5f);
    const float gw = bgm.w * rsqrtf(bv.w + 1e-5f);
    for (int n = rg * 4; n < rg * 4 + 4; ++n) {
      const int e0 = s_rp[n], e1 = s_rp[n + 1];
      float4 acc = make_float4(0.f, 0.f, 0.f, 0.f);
      for (int e = e0; e < e1; ++e) {
        const int s = s_src[e];
        const float al = s_alpha[e * NH + hh];
        const float4 v = *(const float4*)(sg + s * RSW + c0);
        FMA4(al, v, acc);
      }
      uint4 pk;
      pk.x = pack_hl(fmaxf((acc.x + bb.x - bm.x) * gx + bbt.x, 0.f));
      pk.y = pack_hl(fmaxf((acc.y + bb.y - bm.y) * gy + bbt.y, 0.f));
      pk.z = pack_hl(fmaxf((acc.z + bb.z - bm.z) * gz + bbt.z, 0.f));
      pk.w = pack_hl(fmaxf((acc.w + bb.w - bm.w) * gw + bbt.w, 0.f));
      *(uint4*)(shl + n * RSW + c0) = pk;
    }
  }
  __syncthreads();

  // ======================= GAT layer 1 =======================
  mfma_gemm(shl, sg, wf + 32768, t);
  __syncthreads();

  if (t < FN) {
    const int n = t;
    const float* row = sg + n * RSW;
    float accs = 0.f, accd = 0.f;
    #pragma unroll 8
    for (int s = 0; s < 32; ++s) {
      const int d = ((n + s) & 31) * 4;
      const float4 v  = *(const float4*)(row + d);
      const float4 as = *(const float4*)(g1as + d);
      const float4 ad = *(const float4*)(g1ad + d);
      accs += v.x*as.x + v.y*as.y + v.z*as.z + v.w*as.w;
      accd += v.x*ad.x + v.y*ad.y + v.z*ad.z + v.w*ad.w;
    }
    s_es[n] = accs;
    s_ed[n] = accd;
  }
  __syncthreads();

  if (t < FN) {
    const int n = t;
    const float edv = s_ed[n];
    const int e0 = s_rp[n], e1 = s_rp[n + 1];
    float mv = -1e30f;
    for (int e = e0; e < e1; ++e) {
      float v = s_es[s_src[e]] + edv;
      v = (v > 0.f) ? v : 0.2f * v;
      mv = fmaxf(mv, v);
    }
    float sum = 0.f;
    for (int e = e0; e < e1; ++e) {
      float v = s_es[s_src[e]] + edv;
      v = (v > 0.f) ? v : 0.2f * v;
      const float ex = __expf(v - mv);
      s_alpha[e] = ex;
      sum += ex;
    }
    const float r = 1.f / sum;
    for (int e = e0; e < e1; ++e) s_alpha[e] *= r;
  }
  __syncthreads();

  {
    const int cg = t & 31, c0 = cg * 4;
    const int rg = t >> 5;
    const float4 bb = *(const float4*)&g1b[c0];
    const float4 bm = *(const float4*)&bn1m[c0];
    const float4 bv = *(const float4*)&bn1v[c0];
    const float4 bgm = *(const float4*)&bn1g[c0];
    const float4 bbt = *(const float4*)&bn1b[c0];
    const float gx = bgm.x * rsqrtf(bv.x + 1e-5f);
    const float gy = bgm.y * rsqrtf(bv.y + 1e-5f);
    const float gz = bgm.z * rsqrtf(bv.z + 1e-5f);
    const float gw = bgm.w * rsqrtf(bv.w + 1e-5f);
    for (int n = rg * 4; n < rg * 4 + 4; ++n) {
      const int e0 = s_rp[n], e1 = s_rp[n + 1];
      float4 acc = make_float4(0.f, 0.f, 0.f, 0.f);
      for (int e = e0; e < e1; ++e) {
        const int s = s_src[e];
        const float al = s_alpha[e];
        const float4 v = *(const float4*)(sg + s * RSW + c0);
        FMA4(al, v, acc);
      }
      uint4 pk;
      pk.x = pack_hl(fmaxf((acc.x + bb.x - bm.x) * gx + bbt.x, 0.f));
      pk.y = pack_hl(fmaxf((acc.y + bb.y - bm.y) * gy + bbt.y, 0.f));
      pk.z = pack_hl(fmaxf((acc.z + bb.z - bm.z) * gz + bbt.z, 0.f));
      pk.w = pack_hl(fmaxf((acc.w + bb.w - bm.w) * gw + bbt.w, 0.f));
      *(uint4*)(shl + n * RSW + c0) = pk;
    }
  }
  __syncthreads();

  // ---- mean pool (from packed shl) + MLP head
  float* s_red = s_alpha;
  {
    const int j = t & 127, q = t >> 7;
    float p = 0.f;
    for (int n = q * 16; n < q * 16 + 16; ++n) p += unpack_val(shl[n * RSW + j]);
    s_red[q * 128 + j] = p;
  }
  __syncthreads();
  if (t < FN) {
    float p = 0.f;
    #pragma unroll
    for (int q = 0; q < 8; ++q) p += s_red[q * 128 + t];
    s_es[t] = p * (1.f / 128.f);
  }
  __syncthreads();
  if (t < 512) {
    const int j = t & 63, part = t >> 6;
    float a = 0.f;
    #pragma unroll
    for (int k = part * 16; k < part * 16 + 16; ++k)
      a = fmaf(s_es[k], w1[k * 64 + j], a);
    s_ed[part * 64 + j] = a;
  }
  __syncthreads();
  if (t < 64) {
    float a = b1[t];
    #pragma unroll
    for (int p = 0; p < 8; ++p) a += s_ed[p * 64 + t];
    a = fmaxf(a, 0.f);
    float v = a * w2[t];
    #pragma unroll
    for (int off = 32; off > 0; off >>= 1) v += __shfl_down(v, off, 64);
    if (t == 0) out[b] = v + b2[0];
  }
}

extern "C" void kernel_launch(void* const* d_in, const int* in_sizes, int n_in,
                              void* d_out, int out_size, void* d_ws, size_t ws_size,
                              hipStream_t stream)
{
  const float* x    = (const float*)d_in[0];
  const int*   ei   = (const int*)d_in[1];
  const float* w_in = (const float*)d_in[2];
  const float* b_in = (const float*)d_in[3];
  const float* g0w  = (const float*)d_in[4];
  const float* g0as = (const float*)d_in[5];
  const float* g0ad = (const float*)d_in[6];
  const float* g0b  = (const float*)d_in[7];
  const float* bn0g = (const float*)d_in[8];
  const float* bn0b = (const float*)d_in[9];
  const float* bn0m = (const float*)d_in[10];
  const float* bn0v = (const float*)d_in[11];
  const float* g1w  = (const float*)d_in[12];
  const float* g1as = (const float*)d_in[13];
  const float* g1ad = (const float*)d_in[14];
  const float* g1b  = (const float*)d_in[15];
  const float* bn1g = (const float*)d_in[16];
  const float* bn1b = (const float*)d_in[17];
  const float* bn1m = (const float*)d_in[18];
  const float* bn1v = (const float*)d_in[19];
  const float* w1   = (const float*)d_in[20];
  const float* b1   = (const float*)d_in[21];
  const float* w2   = (const float*)d_in[22];
  const float* b2   = (const float*)d_in[23];

  int* rp   = (int*)d_ws;                      // 129 ints
  int* srcs = rp + 256;                        // 1152 ints
  u16* wf   = (u16*)((char*)d_ws + 8192);      // 2*2*16384 bf16 = 128 KB

  build_csr_kernel<<<1, 256, 0, stream>>>(ei, rp, srcs);
  prep_w_kernel<<<128, 256, 0, stream>>>(g0w, g1w, wf);
  gnn_fused_kernel<<<1024, 1024, 0, stream>>>(x, w_in, b_in,
      g0as, g0ad, g0b, bn0g, bn0b, bn0m, bn0v,
      g1as, g1ad, g1b, bn1g, bn1b, bn1m, bn1v,
      w1, b1, w2, b2, rp, srcs, wf, (float*)d_out);
}

// Round 4
// 226.199 us; speedup vs baseline: 4.7099x; 1.0205x over previous
//
#include <hip/hip_runtime.h>

#define FN   128    // nodes per graph
#define HDIM 128    // hidden dim
#define NH   4      // heads, layer 0
#define HSZ  32     // head dim, layer 0
#define EB   1024   // base edges per graph
#define ET   1152   // edges incl. self loops
#define RSW  132    // padded LDS row stride (words)

typedef __attribute__((ext_vector_type(8))) short bf16x8;
typedef __attribute__((ext_vector_type(4))) float f32x4;
typedef unsigned int u32;
typedef unsigned short u16;

union U8 { bf16x8 v; u32 u[4]; };

__device__ __forceinline__ u32 pack_hl(float v) {
  const u32 u = __float_as_uint(v);
  const u32 hib = u & 0xFFFF0000u;
  const float lo = v - __uint_as_float(hib);
  return hib | (__float_as_uint(lo) >> 16);
}
__device__ __forceinline__ float unpack_val(u32 p) {
  return __uint_as_float(p & 0xFFFF0000u) + __uint_as_float(p << 16);
}

__device__ __forceinline__ void unpack_frag(const u32* __restrict__ q,
                                            bf16x8& hi, bf16x8& lo)
{
  const uint4 p0 = *(const uint4*)(q);
  const uint4 p1 = *(const uint4*)(q + 4);
  U8 H, L;
  H.u[0] = (p0.x >> 16) | (p0.y & 0xFFFF0000u);
  L.u[0] = (p0.x & 0xFFFFu) | (p0.y << 16);
  H.u[1] = (p0.z >> 16) | (p0.w & 0xFFFF0000u);
  L.u[1] = (p0.z & 0xFFFFu) | (p0.w << 16);
  H.u[2] = (p1.x >> 16) | (p1.y & 0xFFFF0000u);
  L.u[2] = (p1.x & 0xFFFFu) | (p1.y << 16);
  H.u[3] = (p1.z >> 16) | (p1.w & 0xFFFF0000u);
  L.u[3] = (p1.z & 0xFFFFu) | (p1.w << 16);
  hi = H.v; lo = L.v;
}

// MFMA GEMM: sg[128][RSW] (f32) = unpack(shl) @ W, W read from global (L2-hot),
// split hi/lo in-register. Wave tile: 32 cols (2 MFMA col-tiles) x 32 rows
// (2 stripes). 16 waves cover 128x128.
__device__ __forceinline__ void mfma_gemm(const u32* __restrict__ shl,
                                          float* __restrict__ sg,
                                          const float* __restrict__ W, int t)
{
  const int w = t >> 6, lane = t & 63;
  const int cg = w & 3, rh = w >> 2;
  const int m = lane & 15, quad = lane >> 4;
  const int n0 = cg * 32;

  bf16x8 bhi[2][4], blo[2][4];
  #pragma unroll
  for (int ct = 0; ct < 2; ++ct) {
    const int n = n0 + ct * 16 + m;
    #pragma unroll
    for (int kc = 0; kc < 4; ++kc) {
      float wv[8];
      #pragma unroll
      for (int j = 0; j < 8; ++j) wv[j] = W[(kc * 32 + quad * 8 + j) * HDIM + n];
      U8 Hh, Ll;
      #pragma unroll
      for (int p = 0; p < 4; ++p) {
        const u32 u0 = __float_as_uint(wv[2 * p]);
        const u32 u1 = __float_as_uint(wv[2 * p + 1]);
        const u32 h0 = u0 & 0xFFFF0000u, h1 = u1 & 0xFFFF0000u;
        const float l0 = wv[2 * p]     - __uint_as_float(h0);
        const float l1 = wv[2 * p + 1] - __uint_as_float(h1);
        Hh.u[p] = (u0 >> 16) | h1;
        Ll.u[p] = (__float_as_uint(l0) >> 16) | (__float_as_uint(l1) & 0xFFFF0000u);
      }
      bhi[ct][kc] = Hh.v; blo[ct][kc] = Ll.v;
    }
  }

  f32x4 acc[2][2];
  #pragma unroll
  for (int s = 0; s < 2; ++s)
    #pragma unroll
    for (int ct = 0; ct < 2; ++ct) acc[s][ct] = (f32x4){0.f, 0.f, 0.f, 0.f};

  #pragma unroll
  for (int s = 0; s < 2; ++s) {
    const int row = rh * 32 + s * 16 + m;
    const u32* ap = shl + row * RSW + quad * 8;
    #pragma unroll
    for (int kc = 0; kc < 4; ++kc) {
      bf16x8 ahi, alo;
      unpack_frag(ap + kc * 32, ahi, alo);
      #pragma unroll
      for (int ct = 0; ct < 2; ++ct) {
        acc[s][ct] = __builtin_amdgcn_mfma_f32_16x16x32_bf16(ahi, bhi[ct][kc], acc[s][ct], 0, 0, 0);
        acc[s][ct] = __builtin_amdgcn_mfma_f32_16x16x32_bf16(alo, bhi[ct][kc], acc[s][ct], 0, 0, 0);
        acc[s][ct] = __builtin_amdgcn_mfma_f32_16x16x32_bf16(ahi, blo[ct][kc], acc[s][ct], 0, 0, 0);
      }
    }
  }
  // C/D layout: col = lane&15, row = quad*4 + reg
  #pragma unroll
  for (int s = 0; s < 2; ++s) {
    const int row0 = rh * 32 + s * 16 + quad * 4;
    #pragma unroll
    for (int ct = 0; ct < 2; ++ct)
      #pragma unroll
      for (int r = 0; r < 4; ++r)
        sg[(row0 + r) * RSW + n0 + ct * 16 + m] = acc[s][ct][r];
  }
}

// ---------------- fully fused per-graph GNN (1024 threads, 16 waves) ----------------
__global__ __launch_bounds__(1024) void gnn_fused_kernel(
    const float* __restrict__ x, const int* __restrict__ ei,
    const float* __restrict__ w_in, const float* __restrict__ b_in,
    const float* __restrict__ g0w, const float* __restrict__ g0as,
    const float* __restrict__ g0ad, const float* __restrict__ g0b,
    const float* __restrict__ bn0g, const float* __restrict__ bn0b,
    const float* __restrict__ bn0m, const float* __restrict__ bn0v,
    const float* __restrict__ g1w, const float* __restrict__ g1as,
    const float* __restrict__ g1ad, const float* __restrict__ g1b,
    const float* __restrict__ bn1g, const float* __restrict__ bn1b,
    const float* __restrict__ bn1m, const float* __restrict__ bn1v,
    const float* __restrict__ w1, const float* __restrict__ b1,
    const float* __restrict__ w2, const float* __restrict__ b2,
    float* __restrict__ out)
{
  __shared__ u32   shl[FN * RSW];       // 67584 B packed hi|lo features
  __shared__ float sg[FN * RSW];        // 67584 B GEMM output (f32)
  __shared__ float s_alpha[NH * ET];    // 18432 B alpha [head][e] (CSR scratch, pool scratch)
  __shared__ int   s_src[ET];
  __shared__ int   s_rp[FN + 1];
  __shared__ float s_es[512];           // [head][n]
  __shared__ float s_ed[512];           // [head][n] -> becomes 1/sum

  const int t = threadIdx.x;
  const int b = blockIdx.x;

  // ================= per-block CSR build =================
  int* s_deg  = (int*)s_alpha;
  int* s_fill = s_deg + 128;
  const int e_dst = ei[EB + t];
  const int e_src = ei[t];
  if (t < 2 * FN) s_deg[t] = 0;        // zeros deg and fill
  __syncthreads();
  atomicAdd(&s_deg[e_dst], 1);

  // ---- input projection + ReLU -> shl (independent of CSR)
  {
    const int j = t & 127, q = t >> 7;
    const float wv = w_in[j], bv = b_in[j];
    for (int n = q * 16; n < q * 16 + 16; ++n) {
      const float v = fmaxf(fmaf(x[(size_t)b * FN + n], wv, bv), 0.f);
      shl[n * RSW + j] = pack_hl(v);
    }
  }
  __syncthreads();
  if (t < 64) {                         // wave-0 exclusive scan of (deg+1)
    const int v0 = s_deg[2 * t] + 1, v1 = s_deg[2 * t + 1] + 1;
    const int p = v0 + v1;
    int sc = p;
    #pragma unroll
    for (int off = 1; off < 64; off <<= 1) {
      const int o = __shfl_up(sc, off, 64);
      if (t >= off) sc += o;
    }
    s_rp[2 * t] = sc - p;
    s_rp[2 * t + 1] = sc - v1;
    if (t == 63) s_rp[128] = sc;        // == ET
  }
  __syncthreads();
  {
    const int p = s_rp[e_dst] + atomicAdd(&s_fill[e_dst], 1);
    s_src[p] = e_src;
  }
  if (t < FN) s_src[s_rp[t + 1] - 1] = t;  // self loop in reserved last slot
  __syncthreads();

  // ======================= GAT layer 0 =======================
  mfma_gemm(shl, sg, g0w, t);
  __syncthreads();

  // logits per (head, node)
  if (t < 512) {
    const int hh = t >> 7, n = t & 127;
    const float* row = sg + n * RSW + hh * HSZ;
    float accs = 0.f, accd = 0.f;
    #pragma unroll
    for (int s = 0; s < 8; ++s) {
      const int d = ((n + s) & 7) * 4;
      const float4 v  = *(const float4*)(row + d);
      const float4 as = *(const float4*)(g0as + hh * HSZ + d);
      const float4 ad = *(const float4*)(g0ad + hh * HSZ + d);
      accs += v.x*as.x + v.y*as.y + v.z*as.z + v.w*as.w;
      accd += v.x*ad.x + v.y*ad.y + v.z*ad.z + v.w*ad.w;
    }
    s_es[hh * 128 + n] = accs;
    s_ed[hh * 128 + n] = accd;
  }
  __syncthreads();

  // softmax: pass1 lrelu+max (stash v), pass2 exp+sum; store 1/sum in s_ed
  if (t < 512) {
    const int hh = t >> 7, n = t & 127;
    const float edv = s_ed[hh * 128 + n];
    const int e0 = s_rp[n], e1 = s_rp[n + 1];
    float mv = -1e30f;
    for (int e = e0; e < e1; ++e) {
      float v = s_es[hh * 128 + s_src[e]] + edv;
      v = (v > 0.f) ? v : 0.2f * v;
      s_alpha[hh * ET + e] = v;
      mv = fmaxf(mv, v);
    }
    float sum = 0.f;
    for (int e = e0; e < e1; ++e) {
      const float ex = __expf(s_alpha[hh * ET + e] - mv);
      s_alpha[hh * ET + e] = ex;
      sum += ex;
    }
    s_ed[hh * 128 + n] = 1.f / sum;
  }
  __syncthreads();

  // aggregation + bias + BN + ReLU -> shl   (thread: 2 nodes x 8 cols)
  {
    const int cg = t & 15, c0 = cg * 8, hh = cg >> 2;
    const int rg = t >> 4;
    const float4 bbA = *(const float4*)&g0b[c0],  bbB = *(const float4*)&g0b[c0 + 4];
    const float4 bmA = *(const float4*)&bn0m[c0], bmB = *(const float4*)&bn0m[c0 + 4];
    const float4 bvA = *(const float4*)&bn0v[c0], bvB = *(const float4*)&bn0v[c0 + 4];
    const float4 bgA = *(const float4*)&bn0g[c0], bgB = *(const float4*)&bn0g[c0 + 4];
    const float4 btA = *(const float4*)&bn0b[c0], btB = *(const float4*)&bn0b[c0 + 4];
    const float g0_ = bgA.x * rsqrtf(bvA.x + 1e-5f), g1_ = bgA.y * rsqrtf(bvA.y + 1e-5f);
    const float g2_ = bgA.z * rsqrtf(bvA.z + 1e-5f), g3_ = bgA.w * rsqrtf(bvA.w + 1e-5f);
    const float g4_ = bgB.x * rsqrtf(bvB.x + 1e-5f), g5_ = bgB.y * rsqrtf(bvB.y + 1e-5f);
    const float g6_ = bgB.z * rsqrtf(bvB.z + 1e-5f), g7_ = bgB.w * rsqrtf(bvB.w + 1e-5f);
    #pragma unroll
    for (int h2 = 0; h2 < 2; ++h2) {
      const int n = rg + h2 * 64;
      const int e0 = s_rp[n], e1 = s_rp[n + 1];
      const float rsv = s_ed[hh * 128 + n];
      float4 a0 = make_float4(0.f, 0.f, 0.f, 0.f);
      float4 a1 = make_float4(0.f, 0.f, 0.f, 0.f);
      for (int e = e0; e < e1; ++e) {
        const int s = s_src[e];
        const float al = s_alpha[hh * ET + e];
        const float4 v0 = *(const float4*)(sg + s * RSW + c0);
        const float4 v1 = *(const float4*)(sg + s * RSW + c0 + 4);
        a0.x = fmaf(al, v0.x, a0.x); a0.y = fmaf(al, v0.y, a0.y);
        a0.z = fmaf(al, v0.z, a0.z); a0.w = fmaf(al, v0.w, a0.w);
        a1.x = fmaf(al, v1.x, a1.x); a1.y = fmaf(al, v1.y, a1.y);
        a1.z = fmaf(al, v1.z, a1.z); a1.w = fmaf(al, v1.w, a1.w);
      }
      uint4 p0, p1;
      p0.x = pack_hl(fmaxf((a0.x * rsv + bbA.x - bmA.x) * g0_ + btA.x, 0.f));
      p0.y = pack_hl(fmaxf((a0.y * rsv + bbA.y - bmA.y) * g1_ + btA.y, 0.f));
      p0.z = pack_hl(fmaxf((a0.z * rsv + bbA.z - bmA.z) * g2_ + btA.z, 0.f));
      p0.w = pack_hl(fmaxf((a0.w * rsv + bbA.w - bmA.w) * g3_ + btA.w, 0.f));
      p1.x = pack_hl(fmaxf((a1.x * rsv + bbB.x - bmB.x) * g4_ + btB.x, 0.f));
      p1.y = pack_hl(fmaxf((a1.y * rsv + bbB.y - bmB.y) * g5_ + btB.y, 0.f));
      p1.z = pack_hl(fmaxf((a1.z * rsv + bbB.z - bmB.z) * g6_ + btB.z, 0.f));
      p1.w = pack_hl(fmaxf((a1.w * rsv + bbB.w - bmB.w) * g7_ + btB.w, 0.f));
      *(uint4*)(shl + n * RSW + c0) = p0;
      *(uint4*)(shl + n * RSW + c0 + 4) = p1;
    }
  }
  __syncthreads();

  // ======================= GAT layer 1 (1 head) =======================
  mfma_gemm(shl, sg, g1w, t);
  __syncthreads();

  if (t < FN) {
    const int n = t;
    const float* row = sg + n * RSW;
    float accs = 0.f, accd = 0.f;
    #pragma unroll 8
    for (int s = 0; s < 32; ++s) {
      const int d = ((n + s) & 31) * 4;
      const float4 v  = *(const float4*)(row + d);
      const float4 as = *(const float4*)(g1as + d);
      const float4 ad = *(const float4*)(g1ad + d);
      accs += v.x*as.x + v.y*as.y + v.z*as.z + v.w*as.w;
      accd += v.x*ad.x + v.y*ad.y + v.z*ad.z + v.w*ad.w;
    }
    s_es[n] = accs;
    s_ed[n] = accd;
  }
  __syncthreads();

  if (t < FN) {
    const int n = t;
    const float edv = s_ed[n];
    const int e0 = s_rp[n], e1 = s_rp[n + 1];
    float mv = -1e30f;
    for (int e = e0; e < e1; ++e) {
      float v = s_es[s_src[e]] + edv;
      v = (v > 0.f) ? v : 0.2f * v;
      s_alpha[e] = v;
      mv = fmaxf(mv, v);
    }
    float sum = 0.f;
    for (int e = e0; e < e1; ++e) {
      const float ex = __expf(s_alpha[e] - mv);
      s_alpha[e] = ex;
      sum += ex;
    }
    s_ed[n] = 1.f / sum;
  }
  __syncthreads();

  {
    const int cg = t & 15, c0 = cg * 8;
    const int rg = t >> 4;
    const float4 bbA = *(const float4*)&g1b[c0],  bbB = *(const float4*)&g1b[c0 + 4];
    const float4 bmA = *(const float4*)&bn1m[c0], bmB = *(const float4*)&bn1m[c0 + 4];
    const float4 bvA = *(const float4*)&bn1v[c0], bvB = *(const float4*)&bn1v[c0 + 4];
    const float4 bgA = *(const float4*)&bn1g[c0], bgB = *(const float4*)&bn1g[c0 + 4];
    const float4 btA = *(const float4*)&bn1b[c0], btB = *(const float4*)&bn1b[c0 + 4];
    const float g0_ = bgA.x * rsqrtf(bvA.x + 1e-5f), g1_ = bgA.y * rsqrtf(bvA.y + 1e-5f);
    const float g2_ = bgA.z * rsqrtf(bvA.z + 1e-5f), g3_ = bgA.w * rsqrtf(bvA.w + 1e-5f);
    const float g4_ = bgB.x * rsqrtf(bvB.x + 1e-5f), g5_ = bgB.y * rsqrtf(bvB.y + 1e-5f);
    const float g6_ = bgB.z * rsqrtf(bvB.z + 1e-5f), g7_ = bgB.w * rsqrtf(bvB.w + 1e-5f);
    #pragma unroll
    for (int h2 = 0; h2 < 2; ++h2) {
      const int n = rg + h2 * 64;
      const int e0 = s_rp[n], e1 = s_rp[n + 1];
      const float rsv = s_ed[n];
      float4 a0 = make_float4(0.f, 0.f, 0.f, 0.f);
      float4 a1 = make_float4(0.f, 0.f, 0.f, 0.f);
      for (int e = e0; e < e1; ++e) {
        const int s = s_src[e];
        const float al = s_alpha[e];
        const float4 v0 = *(const float4*)(sg + s * RSW + c0);
        const float4 v1 = *(const float4*)(sg + s * RSW + c0 + 4);
        a0.x = fmaf(al, v0.x, a0.x); a0.y = fmaf(al, v0.y, a0.y);
        a0.z = fmaf(al, v0.z, a0.z); a0.w = fmaf(al, v0.w, a0.w);
        a1.x = fmaf(al, v1.x, a1.x); a1.y = fmaf(al, v1.y, a1.y);
        a1.z = fmaf(al, v1.z, a1.z); a1.w = fmaf(al, v1.w, a1.w);
      }
      uint4 p0, p1;
      p0.x = pack_hl(fmaxf((a0.x * rsv + bbA.x - bmA.x) * g0_ + btA.x, 0.f));
      p0.y = pack_hl(fmaxf((a0.y * rsv + bbA.y - bmA.y) * g1_ + btA.y, 0.f));
      p0.z = pack_hl(fmaxf((a0.z * rsv + bbA.z - bmA.z) * g2_ + btA.z, 0.f));
      p0.w = pack_hl(fmaxf((a0.w * rsv + bbA.w - bmA.w) * g3_ + btA.w, 0.f));
      p1.x = pack_hl(fmaxf((a1.x * rsv + bbB.x - bmB.x) * g4_ + btB.x, 0.f));
      p1.y = pack_hl(fmaxf((a1.y * rsv + bbB.y - bmB.y) * g5_ + btB.y, 0.f));
      p1.z = pack_hl(fmaxf((a1.z * rsv + bbB.z - bmB.z) * g6_ + btB.z, 0.f));
      p1.w = pack_hl(fmaxf((a1.w * rsv + bbB.w - bmB.w) * g7_ + btB.w, 0.f));
      *(uint4*)(shl + n * RSW + c0) = p0;
      *(uint4*)(shl + n * RSW + c0 + 4) = p1;
    }
  }
  __syncthreads();

  // ---- mean pool (packed shl) + MLP head
  float* s_red = s_alpha;
  {
    const int j = t & 127, q = t >> 7;
    float p = 0.f;
    for (int n = q * 16; n < q * 16 + 16; ++n) p += unpack_val(shl[n * RSW + j]);
    s_red[q * 128 + j] = p;
  }
  __syncthreads();
  if (t < FN) {
    float p = 0.f;
    #pragma unroll
    for (int q = 0; q < 8; ++q) p += s_red[q * 128 + t];
    s_es[t] = p * (1.f / 128.f);
  }
  __syncthreads();
  if (t < 512) {
    const int j = t & 63, part = t >> 6;
    float a = 0.f;
    #pragma unroll
    for (int k = part * 16; k < part * 16 + 16; ++k)
      a = fmaf(s_es[k], w1[k * 64 + j], a);
    s_ed[part * 64 + j] = a;
  }
  __syncthreads();
  if (t < 64) {
    float a = b1[t];
    #pragma unroll
    for (int p = 0; p < 8; ++p) a += s_ed[p * 64 + t];
    a = fmaxf(a, 0.f);
    float v = a * w2[t];
    #pragma unroll
    for (int off = 32; off > 0; off >>= 1) v += __shfl_down(v, off, 64);
    if (t == 0) out[b] = v + b2[0];
  }
}

extern "C" void kernel_launch(void* const* d_in, const int* in_sizes, int n_in,
                              void* d_out, int out_size, void* d_ws, size_t ws_size,
                              hipStream_t stream)
{
  const float* x    = (const float*)d_in[0];
  const int*   ei   = (const int*)d_in[1];
  const float* w_in = (const float*)d_in[2];
  const float* b_in = (const float*)d_in[3];
  const float* g0w  = (const float*)d_in[4];
  const float* g0as = (const float*)d_in[5];
  const float* g0ad = (const float*)d_in[6];
  const float* g0b  = (const float*)d_in[7];
  const float* bn0g = (const float*)d_in[8];
  const float* bn0b = (const float*)d_in[9];
  const float* bn0m = (const float*)d_in[10];
  const float* bn0v = (const float*)d_in[11];
  const float* g1w  = (const float*)d_in[12];
  const float* g1as = (const float*)d_in[13];
  const float* g1ad = (const float*)d_in[14];
  const float* g1b  = (const float*)d_in[15];
  const float* bn1g = (const float*)d_in[16];
  const float* bn1b = (const float*)d_in[17];
  const float* bn1m = (const float*)d_in[18];
  const float* bn1v = (const float*)d_in[19];
  const float* w1   = (const float*)d_in[20];
  const float* b1   = (const float*)d_in[21];
  const float* w2   = (const float*)d_in[22];
  const float* b2   = (const float*)d_in[23];

  gnn_fused_kernel<<<1024, 1024, 0, stream>>>(x, ei, w_in, b_in,
      g0w, g0as, g0ad, g0b, bn0g, bn0b, bn0m, bn0v,
      g1w, g1as, g1ad, g1b, bn1g, bn1b, bn1m, bn1v,
      w1, b1, w2, b2, (float*)d_out);
}

// Round 5
// 214.026 us; speedup vs baseline: 4.9777x; 1.0569x over previous
//
#include <hip/hip_runtime.h>

#define FN   128    // nodes per graph
#define HDIM 128    // hidden dim
#define NH   4      // heads, layer 0
#define HSZ  32     // head dim, layer 0
#define EB   1024   // base edges per graph
#define ET   1152   // edges incl. self loops
#define RSW  132    // padded LDS row stride (words)

typedef __attribute__((ext_vector_type(8))) short bf16x8;
typedef __attribute__((ext_vector_type(4))) float f32x4;
typedef unsigned int u32;
typedef unsigned short u16;

union U8 { bf16x8 v; u32 u[4]; };

__device__ __forceinline__ u32 pack_hl(float v) {
  const u32 u = __float_as_uint(v);
  const u32 hib = u & 0xFFFF0000u;
  const float lo = v - __uint_as_float(hib);
  return hib | (__float_as_uint(lo) >> 16);
}
__device__ __forceinline__ float unpack_val(u32 p) {
  return __uint_as_float(p & 0xFFFF0000u) + __uint_as_float(p << 16);
}

__device__ __forceinline__ void unpack_frag(const u32* __restrict__ q,
                                            bf16x8& hi, bf16x8& lo)
{
  const uint4 p0 = *(const uint4*)(q);
  const uint4 p1 = *(const uint4*)(q + 4);
  U8 H, L;
  H.u[0] = (p0.x >> 16) | (p0.y & 0xFFFF0000u);
  L.u[0] = (p0.x & 0xFFFFu) | (p0.y << 16);
  H.u[1] = (p0.z >> 16) | (p0.w & 0xFFFF0000u);
  L.u[1] = (p0.z & 0xFFFFu) | (p0.w << 16);
  H.u[2] = (p1.x >> 16) | (p1.y & 0xFFFF0000u);
  L.u[2] = (p1.x & 0xFFFFu) | (p1.y << 16);
  H.u[3] = (p1.z >> 16) | (p1.w & 0xFFFF0000u);
  L.u[3] = (p1.z & 0xFFFFu) | (p1.w << 16);
  hi = H.v; lo = L.v;
}

// MFMA GEMM: sg[128][RSW] (f32) = unpack(shl) @ W, W from global (L2-hot),
// split hi/lo in-register. Wave tile 32 cols x 32 rows; kc-OUTER loop keeps
// only one kc's B-frags live (32 VGPRs) -> no spill.
__device__ __forceinline__ void mfma_gemm(const u32* __restrict__ shl,
                                          float* __restrict__ sg,
                                          const float* __restrict__ W, int t)
{
  const int w = t >> 6, lane = t & 63;
  const int cg = w & 3, rh = w >> 2;
  const int m = lane & 15, quad = lane >> 4;
  const int n0 = cg * 32;

  f32x4 acc[2][2];
  #pragma unroll
  for (int s = 0; s < 2; ++s)
    #pragma unroll
    for (int ct = 0; ct < 2; ++ct) acc[s][ct] = (f32x4){0.f, 0.f, 0.f, 0.f};

  const u32* ap0 = shl + (rh * 32 + m) * RSW + quad * 8;
  const u32* ap1 = shl + (rh * 32 + 16 + m) * RSW + quad * 8;

  #pragma unroll
  for (int kc = 0; kc < 4; ++kc) {
    bf16x8 bhi[2], blo[2];
    #pragma unroll
    for (int ct = 0; ct < 2; ++ct) {
      const int n = n0 + ct * 16 + m;
      float wv[8];
      #pragma unroll
      for (int j = 0; j < 8; ++j) wv[j] = W[(kc * 32 + quad * 8 + j) * HDIM + n];
      U8 Hh, Ll;
      #pragma unroll
      for (int p = 0; p < 4; ++p) {
        const u32 u0 = __float_as_uint(wv[2 * p]);
        const u32 u1 = __float_as_uint(wv[2 * p + 1]);
        const u32 h0 = u0 & 0xFFFF0000u, h1 = u1 & 0xFFFF0000u;
        const float l0 = wv[2 * p]     - __uint_as_float(h0);
        const float l1 = wv[2 * p + 1] - __uint_as_float(h1);
        Hh.u[p] = (u0 >> 16) | h1;
        Ll.u[p] = (__float_as_uint(l0) >> 16) | (__float_as_uint(l1) & 0xFFFF0000u);
      }
      bhi[ct] = Hh.v; blo[ct] = Ll.v;
    }
    bf16x8 a0hi, a0lo, a1hi, a1lo;
    unpack_frag(ap0 + kc * 32, a0hi, a0lo);
    unpack_frag(ap1 + kc * 32, a1hi, a1lo);
    #pragma unroll
    for (int ct = 0; ct < 2; ++ct) {
      acc[0][ct] = __builtin_amdgcn_mfma_f32_16x16x32_bf16(a0hi, bhi[ct], acc[0][ct], 0, 0, 0);
      acc[0][ct] = __builtin_amdgcn_mfma_f32_16x16x32_bf16(a0lo, bhi[ct], acc[0][ct], 0, 0, 0);
      acc[0][ct] = __builtin_amdgcn_mfma_f32_16x16x32_bf16(a0hi, blo[ct], acc[0][ct], 0, 0, 0);
      acc[1][ct] = __builtin_amdgcn_mfma_f32_16x16x32_bf16(a1hi, bhi[ct], acc[1][ct], 0, 0, 0);
      acc[1][ct] = __builtin_amdgcn_mfma_f32_16x16x32_bf16(a1lo, bhi[ct], acc[1][ct], 0, 0, 0);
      acc[1][ct] = __builtin_amdgcn_mfma_f32_16x16x32_bf16(a1hi, blo[ct], acc[1][ct], 0, 0, 0);
    }
  }
  // C/D layout: col = lane&15, row = quad*4 + reg
  #pragma unroll
  for (int s = 0; s < 2; ++s) {
    const int row0 = rh * 32 + s * 16 + quad * 4;
    #pragma unroll
    for (int ct = 0; ct < 2; ++ct)
      #pragma unroll
      for (int r = 0; r < 4; ++r)
        sg[(row0 + r) * RSW + n0 + ct * 16 + m] = acc[s][ct][r];
  }
}

// ---------------- fully fused per-graph GNN (1024 threads, 16 waves) ----------------
__global__ __launch_bounds__(1024) void gnn_fused_kernel(
    const float* __restrict__ x, const int* __restrict__ ei,
    const float* __restrict__ w_in, const float* __restrict__ b_in,
    const float* __restrict__ g0w, const float* __restrict__ g0as,
    const float* __restrict__ g0ad, const float* __restrict__ g0b,
    const float* __restrict__ bn0g, const float* __restrict__ bn0b,
    const float* __restrict__ bn0m, const float* __restrict__ bn0v,
    const float* __restrict__ g1w, const float* __restrict__ g1as,
    const float* __restrict__ g1ad, const float* __restrict__ g1b,
    const float* __restrict__ bn1g, const float* __restrict__ bn1b,
    const float* __restrict__ bn1m, const float* __restrict__ bn1v,
    const float* __restrict__ w1, const float* __restrict__ b1,
    const float* __restrict__ w2, const float* __restrict__ b2,
    float* __restrict__ out)
{
  __shared__ u32   shl[FN * RSW];       // 67584 B packed hi|lo features
  __shared__ float sg[FN * RSW];        // 67584 B GEMM output (f32)
  __shared__ float s_alpha[NH * ET];    // 18432 B alpha [head][e]
  __shared__ int   s_src[ET];
  __shared__ int   s_rp[FN + 1];
  __shared__ float s_es[512];           // [head][n]
  __shared__ float s_ed[512];           // [head][n] -> becomes 1/sum

  const int t = threadIdx.x;
  const int b = blockIdx.x;

  // ================= per-block CSR build =================
  int* s_deg  = (int*)s_alpha;
  int* s_fill = s_deg + 128;
  const int e_dst = ei[EB + t];
  const int e_src = ei[t];
  if (t < 2 * FN) s_deg[t] = 0;
  __syncthreads();
  atomicAdd(&s_deg[e_dst], 1);

  // ---- input projection + ReLU -> shl (independent of CSR)
  {
    const int j = t & 127, q = t >> 7;
    const float wv = w_in[j], bv = b_in[j];
    for (int n = q * 16; n < q * 16 + 16; ++n) {
      const float v = fmaxf(fmaf(x[(size_t)b * FN + n], wv, bv), 0.f);
      shl[n * RSW + j] = pack_hl(v);
    }
  }
  __syncthreads();
  if (t < 64) {                         // wave-0 exclusive scan of (deg+1)
    const int v0 = s_deg[2 * t] + 1, v1 = s_deg[2 * t + 1] + 1;
    const int p = v0 + v1;
    int sc = p;
    #pragma unroll
    for (int off = 1; off < 64; off <<= 1) {
      const int o = __shfl_up(sc, off, 64);
      if (t >= off) sc += o;
    }
    s_rp[2 * t] = sc - p;
    s_rp[2 * t + 1] = sc - v1;
    if (t == 63) s_rp[128] = sc;        // == ET
  }
  __syncthreads();
  {
    const int p = s_rp[e_dst] + atomicAdd(&s_fill[e_dst], 1);
    s_src[p] = e_src;
  }
  if (t < FN) s_src[s_rp[t + 1] - 1] = t;  // self loop in reserved last slot
  __syncthreads();

  // ======================= GAT layer 0 =======================
  mfma_gemm(shl, sg, g0w, t);
  __syncthreads();

  // logits per (head, node)
  if (t < 512) {
    const int hh = t >> 7, n = t & 127;
    const float* row = sg + n * RSW + hh * HSZ;
    float accs = 0.f, accd = 0.f;
    #pragma unroll
    for (int s = 0; s < 8; ++s) {
      const int d = ((n + s) & 7) * 4;
      const float4 v  = *(const float4*)(row + d);
      const float4 as = *(const float4*)(g0as + hh * HSZ + d);
      const float4 ad = *(const float4*)(g0ad + hh * HSZ + d);
      accs += v.x*as.x + v.y*as.y + v.z*as.z + v.w*as.w;
      accd += v.x*ad.x + v.y*ad.y + v.z*ad.z + v.w*ad.w;
    }
    s_es[hh * 128 + n] = accs;
    s_ed[hh * 128 + n] = accd;
  }
  __syncthreads();

  // softmax: pass1 lrelu+max (stash v), pass2 exp+sum; store 1/sum in s_ed
  if (t < 512) {
    const int hh = t >> 7, n = t & 127;
    const float edv = s_ed[hh * 128 + n];
    const int e0 = s_rp[n], e1 = s_rp[n + 1];
    float mv = -1e30f;
    int e = e0;
    for (; e + 2 <= e1; e += 2) {
      const int sA = s_src[e], sB = s_src[e + 1];
      float vA = s_es[hh * 128 + sA] + edv;
      float vB = s_es[hh * 128 + sB] + edv;
      vA = (vA > 0.f) ? vA : 0.2f * vA;
      vB = (vB > 0.f) ? vB : 0.2f * vB;
      s_alpha[hh * ET + e] = vA;
      s_alpha[hh * ET + e + 1] = vB;
      mv = fmaxf(mv, fmaxf(vA, vB));
    }
    if (e < e1) {
      float vA = s_es[hh * 128 + s_src[e]] + edv;
      vA = (vA > 0.f) ? vA : 0.2f * vA;
      s_alpha[hh * ET + e] = vA;
      mv = fmaxf(mv, vA);
    }
    float sum = 0.f;
    e = e0;
    for (; e + 2 <= e1; e += 2) {
      const float exA = __expf(s_alpha[hh * ET + e] - mv);
      const float exB = __expf(s_alpha[hh * ET + e + 1] - mv);
      s_alpha[hh * ET + e] = exA;
      s_alpha[hh * ET + e + 1] = exB;
      sum += exA + exB;
    }
    if (e < e1) {
      const float exA = __expf(s_alpha[hh * ET + e] - mv);
      s_alpha[hh * ET + e] = exA;
      sum += exA;
    }
    s_ed[hh * 128 + n] = 1.f / sum;
  }
  __syncthreads();

  // aggregation + bias + BN + ReLU -> shl
  // thread: 2 nodes x 8 cols, cols split {cg*4, 64+cg*4} (2-way banks = free)
  {
    const int cg = t & 15, rg = t >> 4;
    const int c0 = cg * 4, c1 = 64 + cg * 4;
    const int hhA = cg >> 3, hhB = 2 + (cg >> 3);
    const float4 bbA = *(const float4*)&g0b[c0],  bbB = *(const float4*)&g0b[c1];
    const float4 bmA = *(const float4*)&bn0m[c0], bmB = *(const float4*)&bn0m[c1];
    const float4 bvA = *(const float4*)&bn0v[c0], bvB = *(const float4*)&bn0v[c1];
    const float4 bgA = *(const float4*)&bn0g[c0], bgB = *(const float4*)&bn0g[c1];
    const float4 btA = *(const float4*)&bn0b[c0], btB = *(const float4*)&bn0b[c1];
    const float g0_ = bgA.x * rsqrtf(bvA.x + 1e-5f), g1_ = bgA.y * rsqrtf(bvA.y + 1e-5f);
    const float g2_ = bgA.z * rsqrtf(bvA.z + 1e-5f), g3_ = bgA.w * rsqrtf(bvA.w + 1e-5f);
    const float g4_ = bgB.x * rsqrtf(bvB.x + 1e-5f), g5_ = bgB.y * rsqrtf(bvB.y + 1e-5f);
    const float g6_ = bgB.z * rsqrtf(bvB.z + 1e-5f), g7_ = bgB.w * rsqrtf(bvB.w + 1e-5f);
    #pragma unroll
    for (int h2 = 0; h2 < 2; ++h2) {
      const int n = rg + h2 * 64;
      const int e0 = s_rp[n], e1 = s_rp[n + 1];
      const float rsvA = s_ed[hhA * 128 + n];
      const float rsvB = s_ed[hhB * 128 + n];
      float4 a0 = make_float4(0.f, 0.f, 0.f, 0.f);
      float4 a1 = make_float4(0.f, 0.f, 0.f, 0.f);
      for (int e = e0; e < e1; ++e) {
        const int s = s_src[e];
        const float alA = s_alpha[hhA * ET + e];
        const float alB = s_alpha[hhB * ET + e];
        const float4 v0 = *(const float4*)(sg + s * RSW + c0);
        const float4 v1 = *(const float4*)(sg + s * RSW + c1);
        a0.x = fmaf(alA, v0.x, a0.x); a0.y = fmaf(alA, v0.y, a0.y);
        a0.z = fmaf(alA, v0.z, a0.z); a0.w = fmaf(alA, v0.w, a0.w);
        a1.x = fmaf(alB, v1.x, a1.x); a1.y = fmaf(alB, v1.y, a1.y);
        a1.z = fmaf(alB, v1.z, a1.z); a1.w = fmaf(alB, v1.w, a1.w);
      }
      uint4 p0, p1;
      p0.x = pack_hl(fmaxf((a0.x * rsvA + bbA.x - bmA.x) * g0_ + btA.x, 0.f));
      p0.y = pack_hl(fmaxf((a0.y * rsvA + bbA.y - bmA.y) * g1_ + btA.y, 0.f));
      p0.z = pack_hl(fmaxf((a0.z * rsvA + bbA.z - bmA.z) * g2_ + btA.z, 0.f));
      p0.w = pack_hl(fmaxf((a0.w * rsvA + bbA.w - bmA.w) * g3_ + btA.w, 0.f));
      p1.x = pack_hl(fmaxf((a1.x * rsvB + bbB.x - bmB.x) * g4_ + btB.x, 0.f));
      p1.y = pack_hl(fmaxf((a1.y * rsvB + bbB.y - bmB.y) * g5_ + btB.y, 0.f));
      p1.z = pack_hl(fmaxf((a1.z * rsvB + bbB.z - bmB.z) * g6_ + btB.z, 0.f));
      p1.w = pack_hl(fmaxf((a1.w * rsvB + bbB.w - bmB.w) * g7_ + btB.w, 0.f));
      *(uint4*)(shl + n * RSW + c0) = p0;
      *(uint4*)(shl + n * RSW + c1) = p1;
    }
  }
  __syncthreads();

  // ======================= GAT layer 1 (1 head) =======================
  mfma_gemm(shl, sg, g1w, t);
  __syncthreads();

  if (t < FN) {
    const int n = t;
    const float* row = sg + n * RSW;
    float accs = 0.f, accd = 0.f;
    #pragma unroll 8
    for (int s = 0; s < 32; ++s) {
      const int d = ((n + s) & 31) * 4;
      const float4 v  = *(const float4*)(row + d);
      const float4 as = *(const float4*)(g1as + d);
      const float4 ad = *(const float4*)(g1ad + d);
      accs += v.x*as.x + v.y*as.y + v.z*as.z + v.w*as.w;
      accd += v.x*ad.x + v.y*ad.y + v.z*ad.z + v.w*ad.w;
    }
    s_es[n] = accs;
    s_ed[n] = accd;
  }
  __syncthreads();

  if (t < FN) {
    const int n = t;
    const float edv = s_ed[n];
    const int e0 = s_rp[n], e1 = s_rp[n + 1];
    float mv = -1e30f;
    int e = e0;
    for (; e + 2 <= e1; e += 2) {
      const int sA = s_src[e], sB = s_src[e + 1];
      float vA = s_es[sA] + edv;
      float vB = s_es[sB] + edv;
      vA = (vA > 0.f) ? vA : 0.2f * vA;
      vB = (vB > 0.f) ? vB : 0.2f * vB;
      s_alpha[e] = vA;
      s_alpha[e + 1] = vB;
      mv = fmaxf(mv, fmaxf(vA, vB));
    }
    if (e < e1) {
      float vA = s_es[s_src[e]] + edv;
      vA = (vA > 0.f) ? vA : 0.2f * vA;
      s_alpha[e] = vA;
      mv = fmaxf(mv, vA);
    }
    float sum = 0.f;
    e = e0;
    for (; e + 2 <= e1; e += 2) {
      const float exA = __expf(s_alpha[e] - mv);
      const float exB = __expf(s_alpha[e + 1] - mv);
      s_alpha[e] = exA;
      s_alpha[e + 1] = exB;
      sum += exA + exB;
    }
    if (e < e1) {
      const float exA = __expf(s_alpha[e] - mv);
      s_alpha[e] = exA;
      sum += exA;
    }
    s_ed[n] = 1.f / sum;
  }
  __syncthreads();

  {
    const int cg = t & 15, rg = t >> 4;
    const int c0 = cg * 4, c1 = 64 + cg * 4;
    const float4 bbA = *(const float4*)&g1b[c0],  bbB = *(const float4*)&g1b[c1];
    const float4 bmA = *(const float4*)&bn1m[c0], bmB = *(const float4*)&bn1m[c1];
    const float4 bvA = *(const float4*)&bn1v[c0], bvB = *(const float4*)&bn1v[c1];
    const float4 bgA = *(const float4*)&bn1g[c0], bgB = *(const float4*)&bn1g[c1];
    const float4 btA = *(const float4*)&bn1b[c0], btB = *(const float4*)&bn1b[c1];
    const float g0_ = bgA.x * rsqrtf(bvA.x + 1e-5f), g1_ = bgA.y * rsqrtf(bvA.y + 1e-5f);
    const float g2_ = bgA.z * rsqrtf(bvA.z + 1e-5f), g3_ = bgA.w * rsqrtf(bvA.w + 1e-5f);
    const float g4_ = bgB.x * rsqrtf(bvB.x + 1e-5f), g5_ = bgB.y * rsqrtf(bvB.y + 1e-5f);
    const float g6_ = bgB.z * rsqrtf(bvB.z + 1e-5f), g7_ = bgB.w * rsqrtf(bvB.w + 1e-5f);
    #pragma unroll
    for (int h2 = 0; h2 < 2; ++h2) {
      const int n = rg + h2 * 64;
      const int e0 = s_rp[n], e1 = s_rp[n + 1];
      const float rsv = s_ed[n];
      float4 a0 = make_float4(0.f, 0.f, 0.f, 0.f);
      float4 a1 = make_float4(0.f, 0.f, 0.f, 0.f);
      for (int e = e0; e < e1; ++e) {
        const int s = s_src[e];
        const float al = s_alpha[e];
        const float4 v0 = *(const float4*)(sg + s * RSW + c0);
        const float4 v1 = *(const float4*)(sg + s * RSW + c1);
        a0.x = fmaf(al, v0.x, a0.x); a0.y = fmaf(al, v0.y, a0.y);
        a0.z = fmaf(al, v0.z, a0.z); a0.w = fmaf(al, v0.w, a0.w);
        a1.x = fmaf(al, v1.x, a1.x); a1.y = fmaf(al, v1.y, a1.y);
        a1.z = fmaf(al, v1.z, a1.z); a1.w = fmaf(al, v1.w, a1.w);
      }
      uint4 p0, p1;
      p0.x = pack_hl(fmaxf((a0.x * rsv + bbA.x - bmA.x) * g0_ + btA.x, 0.f));
      p0.y = pack_hl(fmaxf((a0.y * rsv + bbA.y - bmA.y) * g1_ + btA.y, 0.f));
      p0.z = pack_hl(fmaxf((a0.z * rsv + bbA.z - bmA.z) * g2_ + btA.z, 0.f));
      p0.w = pack_hl(fmaxf((a0.w * rsv + bbA.w - bmA.w) * g3_ + btA.w, 0.f));
      p1.x = pack_hl(fmaxf((a1.x * rsv + bbB.x - bmB.x) * g4_ + btB.x, 0.f));
      p1.y = pack_hl(fmaxf((a1.y * rsv + bbB.y - bmB.y) * g5_ + btB.y, 0.f));
      p1.z = pack_hl(fmaxf((a1.z * rsv + bbB.z - bmB.z) * g6_ + btB.z, 0.f));
      p1.w = pack_hl(fmaxf((a1.w * rsv + bbB.w - bmB.w) * g7_ + btB.w, 0.f));
      *(uint4*)(shl + n * RSW + c0) = p0;
      *(uint4*)(shl + n * RSW + c1) = p1;
    }
  }
  __syncthreads();

  // ---- mean pool (packed shl) + MLP head
  float* s_red = s_alpha;
  {
    const int j = t & 127, q = t >> 7;
    float p = 0.f;
    for (int n = q * 16; n < q * 16 + 16; ++n) p += unpack_val(shl[n * RSW + j]);
    s_red[q * 128 + j] = p;
  }
  __syncthreads();
  if (t < FN) {
    float p = 0.f;
    #pragma unroll
    for (int q = 0; q < 8; ++q) p += s_red[q * 128 + t];
    s_es[t] = p * (1.f / 128.f);
  }
  __syncthreads();
  if (t < 512) {
    const int j = t & 63, part = t >> 6;
    float a = 0.f;
    #pragma unroll
    for (int k = part * 16; k < part * 16 + 16; ++k)
      a = fmaf(s_es[k], w1[k * 64 + j], a);
    s_ed[part * 64 + j] = a;
  }
  __syncthreads();
  if (t < 64) {
    float a = b1[t];
    #pragma unroll
    for (int p = 0; p < 8; ++p) a += s_ed[p * 64 + t];
    a = fmaxf(a, 0.f);
    float v = a * w2[t];
    #pragma unroll
    for (int off = 32; off > 0; off >>= 1) v += __shfl_down(v, off, 64);
    if (t == 0) out[b] = v + b2[0];
  }
}

extern "C" void kernel_launch(void* const* d_in, const int* in_sizes, int n_in,
                              void* d_out, int out_size, void* d_ws, size_t ws_size,
                              hipStream_t stream)
{
  const float* x    = (const float*)d_in[0];
  const int*   ei   = (const int*)d_in[1];
  const float* w_in = (const float*)d_in[2];
  const float* b_in = (const float*)d_in[3];
  const float* g0w  = (const float*)d_in[4];
  const float* g0as = (const float*)d_in[5];
  const float* g0ad = (const float*)d_in[6];
  const float* g0b  = (const float*)d_in[7];
  const float* bn0g = (const float*)d_in[8];
  const float* bn0b = (const float*)d_in[9];
  const float* bn0m = (const float*)d_in[10];
  const float* bn0v = (const float*)d_in[11];
  const float* g1w  = (const float*)d_in[12];
  const float* g1as = (const float*)d_in[13];
  const float* g1ad = (const float*)d_in[14];
  const float* g1b  = (const float*)d_in[15];
  const float* bn1g = (const float*)d_in[16];
  const float* bn1b = (const float*)d_in[17];
  const float* bn1m = (const float*)d_in[18];
  const float* bn1v = (const float*)d_in[19];
  const float* w1   = (const float*)d_in[20];
  const float* b1   = (const float*)d_in[21];
  const float* w2   = (const float*)d_in[22];
  const float* b2   = (const float*)d_in[23];

  gnn_fused_kernel<<<1024, 1024, 0, stream>>>(x, ei, w_in, b_in,
      g0w, g0as, g0ad, g0b, bn0g, bn0b, bn0m, bn0v,
      g1w, g1as, g1ad, g1b, bn1g, bn1b, bn1m, bn1v,
      w1, b1, w2, b2, (float*)d_out);
}